// Round 2
// baseline (861.816 us; speedup 1.0000x reference)
//
#include <hip/hip_runtime.h>
#include <hip/hip_bf16.h>

#define B_  2
#define S_  2048
#define E_  1024
#define H_  16
#define DK_ 64
#define BH_ (B_*H_)   // 32
#define M_  (B_*S_)   // 4096

typedef __attribute__((ext_vector_type(8))) short bf16x8;
typedef __attribute__((ext_vector_type(4))) float f32x4;
typedef unsigned short u16;
typedef unsigned int   u32;

__device__ __forceinline__ float bf2f(u16 u) {
    u32 x = ((u32)u) << 16;
    float f;
    __builtin_memcpy(&f, &x, 4);
    return f;
}
__device__ __forceinline__ u16 f2bf(float f) {
    u32 x;
    __builtin_memcpy(&x, &f, 4);
    u32 r = (x + 0x7fffu + ((x >> 16) & 1u)) >> 16;  // round-to-nearest-even
    return (u16)r;
}

// stage 8 fp32 -> 8 bf16 into LDS (16B store)
__device__ __forceinline__ void stage8f(u16* dst, const float* src) {
    float4 f0 = *(const float4*)src;
    float4 f1 = *(const float4*)(src + 4);
    u16 tmp[8] = {f2bf(f0.x), f2bf(f0.y), f2bf(f0.z), f2bf(f0.w),
                  f2bf(f1.x), f2bf(f1.y), f2bf(f1.z), f2bf(f1.w)};
    *(uint4*)dst = *(uint4*)tmp;
}
// read 8 bf16 from LDS -> 8 fp32 global
__device__ __forceinline__ void store8f(float* dst, const u16* src) {
    bf16x8 v = *(const bf16x8*)src;
    float4 lo = {bf2f((u16)v[0]), bf2f((u16)v[1]), bf2f((u16)v[2]), bf2f((u16)v[3])};
    float4 hi = {bf2f((u16)v[4]), bf2f((u16)v[5]), bf2f((u16)v[6]), bf2f((u16)v[7])};
    *(float4*)dst       = lo;
    *(float4*)(dst + 4) = hi;
}

// ---------------------------------------------------------------------------
// Dtype probe: Wq ~ U(-1/32,1/32). If storage is bf16, all u16 decode small.
// If storage is fp32, the mantissa-half u16s decode to random exponents.
// ---------------------------------------------------------------------------
__global__ void probe_kernel(const u16* __restrict__ w, int* __restrict__ flag)
{
    if (threadIdx.x == 0 && blockIdx.x == 0) {
        int big = 0;
        for (int i = 0; i < 128; i++) {
            float v = bf2f(w[i]);
            if (fabsf(v) > 0.25f) big++;
        }
        *flag = (big >= 4) ? 1 : 0;   // 1 = fp32 storage
    }
}

// ---------------------------------------------------------------------------
// C = X (M x K) * W^T (N x K) + bias, MFMA 16x16x32 bf16, 64x64 tile.
// vmode 0: out[((b*H+h)*S + s)*DK + d]   (q,k layout, bf16 ws)
// vmode 1: out[((b*H+h)*DK + d)*S + s]   (v transposed for PV B-operand)
// ---------------------------------------------------------------------------
__global__ __launch_bounds__(256) void proj_kernel(
    const void* __restrict__ Xv, const void* __restrict__ Wv,
    const void* __restrict__ biasv, u16* __restrict__ out, int vmode,
    const int* __restrict__ flag)
{
    __shared__ __align__(16) u16 als[64*72];
    __shared__ __align__(16) u16 bls[64*72];
    const int isf32 = *flag;
    const int t    = threadIdx.x;
    const int m0   = blockIdx.x * 64;
    const int n0   = blockIdx.y * 64;
    const int w    = t >> 6;
    const int ln   = t & 15;
    const int quad = (t >> 4) & 3;
    const int lr   = t >> 3;
    const int c8   = (t & 7) * 8;

    f32x4 acc[4];
    #pragma unroll
    for (int i = 0; i < 4; i++) acc[i] = (f32x4){0.f, 0.f, 0.f, 0.f};

    for (int kt = 0; kt < E_; kt += 64) {
        __syncthreads();
        if (isf32) {
            const float* Xf = (const float*)Xv;
            const float* Wf = (const float*)Wv;
            stage8f(&als[lr*72 + c8],      &Xf[(size_t)(m0+lr)*E_    + kt + c8]);
            stage8f(&als[(lr+32)*72 + c8], &Xf[(size_t)(m0+lr+32)*E_ + kt + c8]);
            stage8f(&bls[lr*72 + c8],      &Wf[(size_t)(n0+lr)*E_    + kt + c8]);
            stage8f(&bls[(lr+32)*72 + c8], &Wf[(size_t)(n0+lr+32)*E_ + kt + c8]);
        } else {
            const u16* X = (const u16*)Xv;
            const u16* W = (const u16*)Wv;
            *(uint4*)&als[lr*72 + c8]      = *(const uint4*)&X[(size_t)(m0+lr)*E_    + kt + c8];
            *(uint4*)&als[(lr+32)*72 + c8] = *(const uint4*)&X[(size_t)(m0+lr+32)*E_ + kt + c8];
            *(uint4*)&bls[lr*72 + c8]      = *(const uint4*)&W[(size_t)(n0+lr)*E_    + kt + c8];
            *(uint4*)&bls[(lr+32)*72 + c8] = *(const uint4*)&W[(size_t)(n0+lr+32)*E_ + kt + c8];
        }
        __syncthreads();
        #pragma unroll
        for (int c = 0; c < 2; c++) {
            bf16x8 a = *(const bf16x8*)&als[(w*16+ln)*72 + c*32 + quad*8];
            #pragma unroll
            for (int cb = 0; cb < 4; cb++) {
                bf16x8 b = *(const bf16x8*)&bls[(cb*16+ln)*72 + c*32 + quad*8];
                acc[cb] = __builtin_amdgcn_mfma_f32_16x16x32_bf16(a, b, acc[cb], 0, 0, 0);
            }
        }
    }

    #pragma unroll
    for (int cb = 0; cb < 4; cb++) {
        const int n  = n0 + cb*16 + ln;
        const float bv = isf32 ? ((const float*)biasv)[n] : bf2f(((const u16*)biasv)[n]);
        const int h = n >> 6;
        const int d = n & 63;
        #pragma unroll
        for (int r = 0; r < 4; r++) {
            const int m  = m0 + w*16 + quad*4 + r;
            const int bb = m >> 11;        // / S_
            const int s  = m & (S_ - 1);
            const float v = acc[cb][r] + bv;
            size_t addr;
            if (vmode == 0) addr = (((size_t)(bb*H_ + h))*S_  + s)*DK_ + d;
            else            addr = (((size_t)(bb*H_ + h))*DK_ + d)*S_  + s;
            out[addr] = f2bf(v);
        }
    }
}

// ---------------------------------------------------------------------------
// RoPE in-place on q (blockIdx.y==0, folds 1/sqrt(DK)=0.125) and k (y==1).
// Workspace is always bf16.
// ---------------------------------------------------------------------------
__global__ __launch_bounds__(256) void rope_kernel(u16* __restrict__ qw, u16* __restrict__ kw)
{
    const int t   = threadIdx.x;
    const int pos = blockIdx.x * 8 + (t >> 5);   // bh*S + s
    const int j   = t & 31;
    const int isq = (blockIdx.y == 0);
    u16* base = (isq ? qw : kw) + (size_t)pos * DK_;
    const int s = pos & (S_ - 1);
    const float scale = isq ? 0.125f : 1.0f;
    if (j < 16) {
        const float invf = powf(10000.0f, -(float)(2*j) / 32.0f);
        const float ang  = (float)s * invf;
        float sn, cs;
        sincosf(ang, &sn, &cs);
        const float x0 = bf2f(base[2*j]);
        const float x1 = bf2f(base[2*j+1]);
        base[2*j]   = f2bf((x0*cs - x1*sn) * scale);
        base[2*j+1] = f2bf((x1*cs + x0*sn) * scale);
    } else if (isq) {
        const int d = j + 16;                    // 32..47
        base[d]      = f2bf(bf2f(base[d])      * 0.125f);
        base[d+16]   = f2bf(bf2f(base[d+16])   * 0.125f);
    }
}

// ---------------------------------------------------------------------------
// Attention: per block one (bh, 64-row q tile). Pass 1: rowsum of exp.
// Pass 2: recompute scores, write normalized attn, accumulate X = P @ V.
// exp clamped at 60 (no-op for sane scores; prevents Inf*0 => NaN if not).
// ---------------------------------------------------------------------------
__global__ __launch_bounds__(256) void attn_kernel(
    const u16* __restrict__ qw, const u16* __restrict__ kw, const u16* __restrict__ vw,
    void* __restrict__ outbase, const int* __restrict__ flag)
{
    __shared__ __align__(16) u16 qls[64*72];
    __shared__ __align__(16) u16 kls[64*72];
    __shared__ __align__(16) u16 vls[64*72];   // [d][kpos]
    __shared__ __align__(16) u16 pls[64*72];   // [qrow][kpos]

    const int isf32 = *flag;
    const int t    = threadIdx.x;
    const int q0   = blockIdx.x * 64;
    const int bh   = blockIdx.y;
    const int w    = t >> 6;
    const int ln   = t & 15;
    const int quad = (t >> 4) & 3;
    const int lr   = t >> 3;
    const int c8   = (t & 7) * 8;

    const u16* qb = qw + (size_t)bh * S_ * DK_;
    const u16* kb = kw + (size_t)bh * S_ * DK_;
    const u16* vb = vw + (size_t)bh * DK_ * S_;

    *(uint4*)&qls[lr*72 + c8]      = *(const uint4*)&qb[(size_t)(q0+lr)*DK_    + c8];
    *(uint4*)&qls[(lr+32)*72 + c8] = *(const uint4*)&qb[(size_t)(q0+lr+32)*DK_ + c8];

    // ---------------- pass 1: row sums ----------------
    float rs[4] = {0.f, 0.f, 0.f, 0.f};
    for (int kt = 0; kt < S_; kt += 64) {
        __syncthreads();
        *(uint4*)&kls[lr*72 + c8]      = *(const uint4*)&kb[(size_t)(kt+lr)*DK_    + c8];
        *(uint4*)&kls[(lr+32)*72 + c8] = *(const uint4*)&kb[(size_t)(kt+lr+32)*DK_ + c8];
        __syncthreads();
        f32x4 sc[4];
        #pragma unroll
        for (int i = 0; i < 4; i++) sc[i] = (f32x4){0.f, 0.f, 0.f, 0.f};
        #pragma unroll
        for (int c = 0; c < 2; c++) {
            bf16x8 a = *(const bf16x8*)&qls[(w*16+ln)*72 + c*32 + quad*8];
            #pragma unroll
            for (int cb = 0; cb < 4; cb++) {
                bf16x8 b = *(const bf16x8*)&kls[(cb*16+ln)*72 + c*32 + quad*8];
                sc[cb] = __builtin_amdgcn_mfma_f32_16x16x32_bf16(a, b, sc[cb], 0, 0, 0);
            }
        }
        #pragma unroll
        for (int cb = 0; cb < 4; cb++)
            #pragma unroll
            for (int r = 0; r < 4; r++)
                rs[r] += expf(fminf(sc[cb][r], 60.0f));
    }
    #pragma unroll
    for (int r = 0; r < 4; r++) {
        rs[r] += __shfl_xor(rs[r], 1, 64);
        rs[r] += __shfl_xor(rs[r], 2, 64);
        rs[r] += __shfl_xor(rs[r], 4, 64);
        rs[r] += __shfl_xor(rs[r], 8, 64);
    }
    float inv[4];
    #pragma unroll
    for (int r = 0; r < 4; r++) inv[r] = 1.0f / rs[r];

    // ---------------- pass 2: attn write + PV ----------------
    f32x4 xacc[4];
    #pragma unroll
    for (int i = 0; i < 4; i++) xacc[i] = (f32x4){0.f, 0.f, 0.f, 0.f};

    for (int kt = 0; kt < S_; kt += 64) {
        __syncthreads();
        *(uint4*)&kls[lr*72 + c8]      = *(const uint4*)&kb[(size_t)(kt+lr)*DK_    + c8];
        *(uint4*)&kls[(lr+32)*72 + c8] = *(const uint4*)&kb[(size_t)(kt+lr+32)*DK_ + c8];
        *(uint4*)&vls[lr*72 + c8]      = *(const uint4*)&vb[(size_t)lr*S_      + kt + c8];
        *(uint4*)&vls[(lr+32)*72 + c8] = *(const uint4*)&vb[(size_t)(lr+32)*S_ + kt + c8];
        __syncthreads();
        f32x4 sc[4];
        #pragma unroll
        for (int i = 0; i < 4; i++) sc[i] = (f32x4){0.f, 0.f, 0.f, 0.f};
        #pragma unroll
        for (int c = 0; c < 2; c++) {
            bf16x8 a = *(const bf16x8*)&qls[(w*16+ln)*72 + c*32 + quad*8];
            #pragma unroll
            for (int cb = 0; cb < 4; cb++) {
                bf16x8 b = *(const bf16x8*)&kls[(cb*16+ln)*72 + c*32 + quad*8];
                sc[cb] = __builtin_amdgcn_mfma_f32_16x16x32_bf16(a, b, sc[cb], 0, 0, 0);
            }
        }
        #pragma unroll
        for (int cb = 0; cb < 4; cb++)
            #pragma unroll
            for (int r = 0; r < 4; r++) {
                const float p = expf(fminf(sc[cb][r], 60.0f)) * inv[r];
                pls[(w*16 + quad*4 + r)*72 + cb*16 + ln] = f2bf(p);
            }
        __syncthreads();
        // attn store
        {
            const size_t a0 = ((size_t)bh*S_ + (q0+lr))*S_ + kt + c8;
            const size_t a1 = ((size_t)bh*S_ + (q0+lr+32))*S_ + kt + c8;
            if (isf32) {
                float* af = (float*)outbase + (size_t)M_*E_;
                store8f(&af[a0], &pls[lr*72 + c8]);
                store8f(&af[a1], &pls[(lr+32)*72 + c8]);
            } else {
                u16* au = (u16*)outbase + (size_t)M_*E_;
                *(uint4*)&au[a0] = *(const uint4*)&pls[lr*72 + c8];
                *(uint4*)&au[a1] = *(const uint4*)&pls[(lr+32)*72 + c8];
            }
        }
        // PV: A = P (row-major), B = V^T tile (vls[d][kpos])
        #pragma unroll
        for (int c = 0; c < 2; c++) {
            bf16x8 a = *(const bf16x8*)&pls[(w*16+ln)*72 + c*32 + quad*8];
            #pragma unroll
            for (int cb = 0; cb < 4; cb++) {
                bf16x8 b = *(const bf16x8*)&vls[(cb*16+ln)*72 + c*32 + quad*8];
                xacc[cb] = __builtin_amdgcn_mfma_f32_16x16x32_bf16(a, b, xacc[cb], 0, 0, 0);
            }
        }
    }

    // X epilogue: out[((b*S + s)*H + h)*DK + d]
    const int bb = bh >> 4;
    const int h  = bh & 15;
    #pragma unroll
    for (int cb = 0; cb < 4; cb++) {
        const int d = cb*16 + ln;
        #pragma unroll
        for (int r = 0; r < 4; r++) {
            const int s = q0 + w*16 + quad*4 + r;
            const size_t idx = (((size_t)bb*S_ + s)*H_ + h)*DK_ + d;
            if (isf32) ((float*)outbase)[idx] = xacc[cb][r];
            else       ((u16*)outbase)[idx]   = f2bf(xacc[cb][r]);
        }
    }
}

extern "C" void kernel_launch(void* const* d_in, const int* in_sizes, int n_in,
                              void* d_out, int out_size, void* d_ws, size_t ws_size,
                              hipStream_t stream)
{
    const void* query = d_in[0];
    const void* key   = d_in[1];
    const void* value = d_in[2];
    const void* Wq    = d_in[3];
    const void* bq    = d_in[4];
    const void* Wk    = d_in[5];
    const void* bk    = d_in[6];
    const void* Wv    = d_in[7];
    const void* bv    = d_in[8];

    int* flag = (int*)d_ws;
    u16* qws  = (u16*)((char*)d_ws + 64);        // bf16 (b,h,s,d), 8 MB
    u16* kws  = qws + (size_t)M_ * E_;           // 8 MB
    u16* vws  = kws + (size_t)M_ * E_;           // bf16 (b,h,d,s), 8 MB

    probe_kernel<<<1, 64, 0, stream>>>((const u16*)Wq, flag);

    dim3 gp(M_/64, E_/64);
    proj_kernel<<<gp, 256, 0, stream>>>(query, Wq, bq, qws, 0, flag);
    proj_kernel<<<gp, 256, 0, stream>>>(key,   Wk, bk, kws, 0, flag);
    proj_kernel<<<gp, 256, 0, stream>>>(value, Wv, bv, vws, 1, flag);
    rope_kernel<<<dim3(BH_*S_/8, 2), 256, 0, stream>>>(qws, kws);
    attn_kernel<<<dim3(S_/64, BH_), 256, 0, stream>>>(qws, kws, vws, d_out, flag);
}